// Round 5
// baseline (8552.184 us; speedup 1.0000x reference)
//
#include <hip/hip_runtime.h>
#include <math.h>

#define N_OBJ 4096
#define F     256
#define NE    8
#define EPT   131072
#define KCAT  (NE * F)      // 2048
#define C_OUT 128
#define FC1_K (N_OBJ * F)   // 1048576

// ---- attribution-round repeat factors (pow2; results scaled back exactly) ----
#define AGG_REP  16
#define GEMM_REP 64
#define FC1_REP  4

typedef __attribute__((ext_vector_type(8))) short s8v;   // 8 bf16 (4 VGPRs) MFMA operand
typedef __attribute__((ext_vector_type(4))) float f4v;   // 4 f32 accumulator

__device__ inline float bf2f(unsigned short u) {
    unsigned int x = ((unsigned int)u) << 16;
    return __builtin_bit_cast(float, x);
}
__device__ inline unsigned short f2bf(float f) {
    unsigned int x = __builtin_bit_cast(unsigned int, f);
    x += 0x7fff + ((x >> 16) & 1);   // RNE
    return (unsigned short)(x >> 16);
}

// ---------------- graph preprocessing (once per launch) ----------------

__global__ __launch_bounds__(256) void k_count_deg(const int* __restrict__ edges,
                                                   int* __restrict__ deg) {
    int gid = blockIdx.x * 256 + threadIdx.x;   // NE*EPT threads
    int e = gid >> 17;                          // EPT = 2^17
    int i = gid & (EPT - 1);
    int dst = edges[(e * 2 + 1) * EPT + i];
    atomicAdd(&deg[e * N_OBJ + dst], 1);
}

__global__ __launch_bounds__(256) void k_scan(const int* __restrict__ deg,
                                              int* __restrict__ rowptr,
                                              int* __restrict__ cursor,
                                              float* __restrict__ invdeg) {
    int e = blockIdx.x;
    int t = threadIdx.x;
    __shared__ int part[256];
    int local[16];
    int base = e * N_OBJ + t * 16;
    int s = 0;
#pragma unroll
    for (int i = 0; i < 16; ++i) { local[i] = deg[base + i]; s += local[i]; }
    part[t] = s;
    __syncthreads();
    for (int off = 1; off < 256; off <<= 1) {
        int v = (t >= off) ? part[t - off] : 0;
        __syncthreads();
        part[t] += v;
        __syncthreads();
    }
    int run = part[t] - s;
#pragma unroll
    for (int i = 0; i < 16; ++i) {
        rowptr[base + i] = run;
        cursor[base + i] = run;
        invdeg[base + i] = 1.0f / fmaxf((float)local[i], 1.0f);
        run += local[i];
    }
}

__global__ __launch_bounds__(256) void k_fill(const int* __restrict__ edges,
                                              int* __restrict__ cursor,
                                              int* __restrict__ col) {
    int gid = blockIdx.x * 256 + threadIdx.x;
    int e = gid >> 17;
    int i = gid & (EPT - 1);
    int src = edges[(e * 2 + 0) * EPT + i];
    int dst = edges[(e * 2 + 1) * EPT + i];
    int pos = atomicAdd(&cursor[e * N_OBJ + dst], 1);
    col[e * EPT + pos] = src;
}

__global__ __launch_bounds__(256) void k_bmask(const int* __restrict__ deg,
                                               unsigned int* __restrict__ bmask) {
    int n = blockIdx.x * 256 + threadIdx.x;
    unsigned int m = 0;
#pragma unroll
    for (int e = 0; e < NE; ++e) m |= (deg[e * N_OBJ + n] > 0) ? (1u << e) : 0u;
    bmask[n] = m;
}

// one fused fp32->bf16 conversion for W0,W1,W2,feat
#define WQ4 (NE * F * F / 4)        // 131072 float4 per W
#define FQ4 (N_OBJ * F / 4)         // 262144 float4 for feat
__global__ __launch_bounds__(256) void k_cvt_all(const float* __restrict__ W0,
                                                 const float* __restrict__ W1,
                                                 const float* __restrict__ W2,
                                                 const float* __restrict__ feat,
                                                 unsigned short* __restrict__ Wb0,
                                                 unsigned short* __restrict__ Wb1,
                                                 unsigned short* __restrict__ Wb2,
                                                 unsigned short* __restrict__ featb) {
    int i = blockIdx.x * 256 + threadIdx.x;
    const float* s;
    unsigned short* d;
    int j;
    if (i < WQ4)            { s = W0;   d = Wb0;   j = i; }
    else if (i < 2 * WQ4)   { s = W1;   d = Wb1;   j = i - WQ4; }
    else if (i < 3 * WQ4)   { s = W2;   d = Wb2;   j = i - 2 * WQ4; }
    else                    { s = feat; d = featb; j = i - 3 * WQ4; }
    float4 v = ((const float4*)s)[j];
    ushort4 o;
    o.x = f2bf(v.x); o.y = f2bf(v.y); o.z = f2bf(v.z); o.w = f2bf(v.w);
    ((ushort4*)d)[j] = o;
}

// ---------------- per-layer: aggregate (AMPLIFIED x AGG_REP) ----------------
__global__ __launch_bounds__(256) void k_aggregate(const unsigned short* __restrict__ h_in,
                                                   const int* __restrict__ rowptr,
                                                   const int* __restrict__ deg,
                                                   const int* __restrict__ col,
                                                   const float* __restrict__ invdeg,
                                                   unsigned short* __restrict__ ah) {
    int wid = blockIdx.x * 4 + (threadIdx.x >> 6);   // == e*N_OBJ + n
    int lane = threadIdx.x & 63;                      // 64 lanes x 4 channels (8B)
    int e = wid >> 12;
    int n = wid & (N_OBJ - 1);
    int beg = rowptr[wid];
    int cnt = deg[wid];
    const int* cl = col + e * EPT + beg;
    const ushort4* h4 = (const ushort4*)h_in;
    float a0 = 0.f, a1 = 0.f, a2 = 0.f, a3 = 0.f;
    for (int rep = 0; rep < AGG_REP; ++rep) {
        int k = 0;
        for (; k + 8 <= cnt; k += 8) {
            int s0 = cl[k],     s1 = cl[k + 1], s2 = cl[k + 2], s3 = cl[k + 3];
            int s4 = cl[k + 4], s5 = cl[k + 5], s6 = cl[k + 6], s7 = cl[k + 7];
            ushort4 v0 = h4[s0 * 64 + lane];
            ushort4 v1 = h4[s1 * 64 + lane];
            ushort4 v2 = h4[s2 * 64 + lane];
            ushort4 v3 = h4[s3 * 64 + lane];
            ushort4 v4 = h4[s4 * 64 + lane];
            ushort4 v5 = h4[s5 * 64 + lane];
            ushort4 v6 = h4[s6 * 64 + lane];
            ushort4 v7 = h4[s7 * 64 + lane];
            a0 += bf2f(v0.x) + bf2f(v1.x) + bf2f(v2.x) + bf2f(v3.x)
                + bf2f(v4.x) + bf2f(v5.x) + bf2f(v6.x) + bf2f(v7.x);
            a1 += bf2f(v0.y) + bf2f(v1.y) + bf2f(v2.y) + bf2f(v3.y)
                + bf2f(v4.y) + bf2f(v5.y) + bf2f(v6.y) + bf2f(v7.y);
            a2 += bf2f(v0.z) + bf2f(v1.z) + bf2f(v2.z) + bf2f(v3.z)
                + bf2f(v4.z) + bf2f(v5.z) + bf2f(v6.z) + bf2f(v7.z);
            a3 += bf2f(v0.w) + bf2f(v1.w) + bf2f(v2.w) + bf2f(v3.w)
                + bf2f(v4.w) + bf2f(v5.w) + bf2f(v6.w) + bf2f(v7.w);
        }
        for (; k < cnt; ++k) {
            ushort4 v = h4[cl[k] * 64 + lane];
            a0 += bf2f(v.x); a1 += bf2f(v.y); a2 += bf2f(v.z); a3 += bf2f(v.w);
        }
        asm volatile("" ::: "memory");   // force reloads next rep; keep passes distinct
    }
    float sc = invdeg[wid] * (1.0f / AGG_REP);   // exact pow2 scale-back
    ushort4 o;
    o.x = f2bf(a0 * sc); o.y = f2bf(a1 * sc); o.z = f2bf(a2 * sc); o.w = f2bf(a3 * sc);
    ((ushort4*)ah)[n * (KCAT / 4) + e * (F / 4) + lane] = o;
}

// ---------------- per-layer GEMM (AMPLIFIED x GEMM_REP) ----------------
template <int OUTBF>
__global__ __launch_bounds__(128) void k_gemm(const unsigned short* __restrict__ A,
                                              const unsigned short* __restrict__ Wb,
                                              const float* __restrict__ bias,
                                              const unsigned int* __restrict__ bmask,
                                              void* __restrict__ Cout) {
    __shared__ short As[32][40];
    __shared__ short Bs[64][40];
    int m0 = blockIdx.x * 32, n0 = blockIdx.y * 64;
    int t = threadIdx.x;
    int wave = t >> 6, lane = t & 63;
    int r = lane & 15, g = lane >> 4;
    int arow = t >> 2, aseg = t & 3;
    int brow = t >> 1, bseg = (t & 1) * 2;
    f4v acc[2][2];
#pragma unroll
    for (int i = 0; i < 2; ++i)
#pragma unroll
        for (int j = 0; j < 2; ++j) acc[i][j] = (f4v){0.f, 0.f, 0.f, 0.f};
    const short* Ap = (const short*)A;
    const short* Wp = (const short*)Wb;
    for (int rep = 0; rep < GEMM_REP; ++rep) {
        for (int k0 = 0; k0 < KCAT; k0 += 32) {
            int e = k0 >> 8, f0 = k0 & 255;
            s8v va = *(const s8v*)(Ap + (size_t)(m0 + arow) * KCAT + k0 + aseg * 8);
            const short* wbase = Wp + (size_t)e * F * F + (size_t)(n0 + brow) * F + f0;
            s8v vb0 = *(const s8v*)(wbase + bseg * 8);
            s8v vb1 = *(const s8v*)(wbase + bseg * 8 + 8);
            __syncthreads();
            *(s8v*)&As[arow][aseg * 8] = va;
            *(s8v*)&Bs[brow][bseg * 8] = vb0;
            *(s8v*)&Bs[brow][bseg * 8 + 8] = vb1;
            __syncthreads();
            s8v bf0 = *(const s8v*)&Bs[wave * 32 + r][g * 8];
            s8v bf1 = *(const s8v*)&Bs[wave * 32 + 16 + r][g * 8];
#pragma unroll
            for (int m = 0; m < 2; ++m) {
                s8v af = *(const s8v*)&As[m * 16 + r][g * 8];
                acc[m][0] = __builtin_amdgcn_mfma_f32_16x16x32_bf16(af, bf0, acc[m][0], 0, 0, 0);
                acc[m][1] = __builtin_amdgcn_mfma_f32_16x16x32_bf16(af, bf1, acc[m][1], 0, 0, 0);
            }
        }
        asm volatile("" ::: "memory");
    }
    const float inv = 1.0f / GEMM_REP;   // exact pow2 scale-back
#pragma unroll
    for (int nn = 0; nn < 2; ++nn) {
        int coln = n0 + wave * 32 + nn * 16 + r;
        float bcol[NE];
#pragma unroll
        for (int e = 0; e < NE; ++e) bcol[e] = bias[e * F + coln];
#pragma unroll
        for (int m = 0; m < 2; ++m) {
#pragma unroll
            for (int reg = 0; reg < 4; ++reg) {
                int mm = m0 + m * 16 + g * 4 + reg;
                unsigned int msk = bmask[mm];
                float v = acc[m][nn][reg] * inv;
#pragma unroll
                for (int e = 0; e < NE; ++e)
                    if ((msk >> e) & 1) v += bcol[e];
                v = fmaxf(v, 0.f);
                if (OUTBF) ((unsigned short*)Cout)[(size_t)mm * F + coln] = f2bf(v);
                else       ((float*)Cout)[(size_t)mm * F + coln] = v;
            }
        }
    }
}

// ---------------- fc1 GEMV (AMPLIFIED x FC1_REP) ----------------
__global__ __launch_bounds__(256) void k_fc1(const float* __restrict__ Wf,
                                             const float* __restrict__ flat,
                                             float* __restrict__ zpart) {
    int c = blockIdx.x;   // 16 chunks of 65536
    int j = blockIdx.y;   // 256 rows
    int t = threadIdx.x;
    const float4* wp = (const float4*)(Wf + (size_t)j * FC1_K + (size_t)c * 65536);
    const float4* fp = (const float4*)(flat + (size_t)c * 65536);
    float s = 0.0f;
    for (int rep = 0; rep < FC1_REP; ++rep) {
#pragma unroll 8
        for (int it = 0; it < 64; ++it) {
            int q = it * 256 + t;
            float4 w4 = wp[q];
            float4 x4 = fp[q];
            s = fmaf(w4.x, x4.x, s);
            s = fmaf(w4.y, x4.y, s);
            s = fmaf(w4.z, x4.z, s);
            s = fmaf(w4.w, x4.w, s);
        }
        asm volatile("" ::: "memory");
    }
    s *= (1.0f / FC1_REP);   // exact pow2 scale-back
#pragma unroll
    for (int off = 32; off > 0; off >>= 1) s += __shfl_down(s, off, 64);
    __shared__ float red[4];
    if ((t & 63) == 0) red[t >> 6] = s;
    __syncthreads();
    if (t == 0) zpart[c * 256 + j] = red[0] + red[1] + red[2] + red[3];
}

__global__ __launch_bounds__(256) void k_final(const float* __restrict__ zpart,
                                               const float* __restrict__ fc1_b,
                                               const float* __restrict__ fc2_w,
                                               const float* __restrict__ fc2_b,
                                               float* __restrict__ out) {
    __shared__ float z[256];
    int t = threadIdx.x;
    float s = fc1_b[t];
#pragma unroll
    for (int c = 0; c < 16; ++c) s += zpart[c * 256 + t];
    z[t] = fmaxf(s, 0.0f);
    __syncthreads();
    if (t < C_OUT) {
        float acc = fc2_b[t];
        for (int k = 0; k < 256; ++k) acc = fmaf(fc2_w[t * 256 + k], z[k], acc);
        out[t] = 1.0f / (1.0f + expf(-acc));
    }
}

extern "C" void kernel_launch(void* const* d_in, const int* in_sizes, int n_in,
                              void* d_out, int out_size, void* d_ws, size_t ws_size,
                              hipStream_t stream) {
    const float* feat  = (const float*)d_in[0];
    const int*   edges = (const int*)d_in[1];
    const float* W0    = (const float*)d_in[2];
    const float* b0    = (const float*)d_in[3];
    const float* W1    = (const float*)d_in[4];
    const float* b1    = (const float*)d_in[5];
    const float* W2    = (const float*)d_in[6];
    const float* b2    = (const float*)d_in[7];
    const float* fc1_w = (const float*)d_in[8];
    const float* fc1_b = (const float*)d_in[9];
    const float* fc2_w = (const float*)d_in[10];
    const float* fc2_b = (const float*)d_in[11];
    float* out = (float*)d_out;

    char* ws = (char*)d_ws;
    size_t off = 0;
    auto alloc = [&](size_t bytes) {
        void* p = ws + off;
        off = (off + bytes + 255) & ~(size_t)255;
        return p;
    };
    int*            deg    = (int*)            alloc(NE * N_OBJ * 4);
    int*            rowptr = (int*)            alloc(NE * N_OBJ * 4);
    int*            cursor = (int*)            alloc(NE * N_OBJ * 4);
    float*          invdeg = (float*)          alloc(NE * N_OBJ * 4);
    int*            col    = (int*)            alloc(NE * EPT * 4);
    unsigned int*   bmask  = (unsigned int*)   alloc(N_OBJ * 4);
    float*          zpart  = (float*)          alloc(16 * 256 * 4);
    unsigned short* Wb0    = (unsigned short*) alloc((size_t)NE * F * F * 2);
    unsigned short* Wb1    = (unsigned short*) alloc((size_t)NE * F * F * 2);
    unsigned short* Wb2    = (unsigned short*) alloc((size_t)NE * F * F * 2);
    unsigned short* featb  = (unsigned short*) alloc((size_t)N_OBJ * F * 2);
    unsigned short* h_ba   = (unsigned short*) alloc((size_t)N_OBJ * F * 2);
    unsigned short* h_bb   = (unsigned short*) alloc((size_t)N_OBJ * F * 2);
    float*          h_f32  = (float*)          alloc((size_t)N_OBJ * F * 4);
    unsigned short* ah     = (unsigned short*) alloc((size_t)N_OBJ * KCAT * 2);
    (void)ws_size; (void)in_sizes; (void)n_in; (void)out_size;

    hipMemsetAsync(deg, 0, NE * N_OBJ * 4, stream);
    k_count_deg<<<NE * EPT / 256, 256, 0, stream>>>(edges, deg);
    k_scan<<<NE, 256, 0, stream>>>(deg, rowptr, cursor, invdeg);
    k_fill<<<NE * EPT / 256, 256, 0, stream>>>(edges, cursor, col);
    k_bmask<<<N_OBJ / 256, 256, 0, stream>>>(deg, bmask);
    k_cvt_all<<<(3 * WQ4 + FQ4) / 256, 256, 0, stream>>>(W0, W1, W2, feat,
                                                         Wb0, Wb1, Wb2, featb);

    dim3 ggrid(N_OBJ / 32, F / 64);   // 512 blocks
    int agrid = NE * N_OBJ / 4;       // one wave per (e,n)

    // layer 0
    k_aggregate<<<agrid, 256, 0, stream>>>(featb, rowptr, deg, col, invdeg, ah);
    k_gemm<1><<<ggrid, 128, 0, stream>>>(ah, Wb0, b0, bmask, h_ba);
    // layer 1
    k_aggregate<<<agrid, 256, 0, stream>>>(h_ba, rowptr, deg, col, invdeg, ah);
    k_gemm<1><<<ggrid, 128, 0, stream>>>(ah, Wb1, b1, bmask, h_bb);
    // layer 2 (fp32 out for fc1)
    k_aggregate<<<agrid, 256, 0, stream>>>(h_bb, rowptr, deg, col, invdeg, ah);
    k_gemm<0><<<ggrid, 128, 0, stream>>>(ah, Wb2, b2, bmask, h_f32);

    dim3 fgrid(16, 256);
    k_fc1<<<fgrid, 256, 0, stream>>>(fc1_w, h_f32, zpart);
    k_final<<<1, 256, 0, stream>>>(zpart, fc1_b, fc2_w, fc2_b, out);
}

// Round 6
// 484.846 us; speedup vs baseline: 17.6390x; 17.6390x over previous
//
#include <hip/hip_runtime.h>
#include <math.h>

#define N_OBJ 4096
#define F     256
#define NE    8
#define EPT   131072
#define KCAT  (NE * F)      // 2048
#define C_OUT 128
#define FC1_K (N_OBJ * F)   // 1048576
#define FCH   16384         // fc1 x-chunk floats (64 KB LDS)
#define FNCH  (FC1_K / FCH) // 64
#define FRJ   8             // fc1 rows per block

typedef __attribute__((ext_vector_type(8))) short s8v;   // 8 bf16 (16 B) MFMA operand
typedef __attribute__((ext_vector_type(4))) float f4v;   // 4 f32 accumulator

__device__ inline float bf2f(unsigned short u) {
    unsigned int x = ((unsigned int)u) << 16;
    return __builtin_bit_cast(float, x);
}
__device__ inline unsigned short f2bf(float f) {
    unsigned int x = __builtin_bit_cast(unsigned int, f);
    x += 0x7fff + ((x >> 16) & 1);   // RNE
    return (unsigned short)(x >> 16);
}
// swizzled short-index of the 16B fragment (row, k8) in a [64 rows][64 bf16] tile.
// 128 B rows: XOR row&7 into the 16B-slot bits -> conflict-free ds_read_b128 (G4).
__device__ __forceinline__ int swz(int row, int k8) {
    return (row * 64 + k8 * 8) ^ ((row & 7) << 3);
}

// ---------------- graph preprocessing (once per launch) ----------------

__global__ __launch_bounds__(256) void k_count_deg(const int* __restrict__ edges,
                                                   int* __restrict__ deg) {
    int gid = blockIdx.x * 256 + threadIdx.x;   // NE*EPT threads
    int e = gid >> 17;                          // EPT = 2^17
    int i = gid & (EPT - 1);
    int dst = edges[(e * 2 + 1) * EPT + i];
    atomicAdd(&deg[e * N_OBJ + dst], 1);
}

__global__ __launch_bounds__(256) void k_scan(const int* __restrict__ deg,
                                              int* __restrict__ rowptr,
                                              int* __restrict__ cursor,
                                              float* __restrict__ invdeg) {
    int e = blockIdx.x;
    int t = threadIdx.x;
    __shared__ int part[256];
    int local[16];
    int base = e * N_OBJ + t * 16;
    int s = 0;
#pragma unroll
    for (int i = 0; i < 16; ++i) { local[i] = deg[base + i]; s += local[i]; }
    part[t] = s;
    __syncthreads();
    for (int off = 1; off < 256; off <<= 1) {
        int v = (t >= off) ? part[t - off] : 0;
        __syncthreads();
        part[t] += v;
        __syncthreads();
    }
    int run = part[t] - s;
#pragma unroll
    for (int i = 0; i < 16; ++i) {
        rowptr[base + i] = run;
        cursor[base + i] = run;
        invdeg[base + i] = 1.0f / fmaxf((float)local[i], 1.0f);
        run += local[i];
    }
}

__global__ __launch_bounds__(256) void k_fill(const int* __restrict__ edges,
                                              int* __restrict__ cursor,
                                              int* __restrict__ col) {
    int gid = blockIdx.x * 256 + threadIdx.x;
    int e = gid >> 17;
    int i = gid & (EPT - 1);
    int src = edges[(e * 2 + 0) * EPT + i];
    int dst = edges[(e * 2 + 1) * EPT + i];
    int pos = atomicAdd(&cursor[e * N_OBJ + dst], 1);
    col[e * EPT + pos] = src;
}

__global__ __launch_bounds__(256) void k_bmask(const int* __restrict__ deg,
                                               unsigned int* __restrict__ bmask) {
    int n = blockIdx.x * 256 + threadIdx.x;
    unsigned int m = 0;
#pragma unroll
    for (int e = 0; e < NE; ++e) m |= (deg[e * N_OBJ + n] > 0) ? (1u << e) : 0u;
    bmask[n] = m;
}

// one fused fp32->bf16 conversion for W0,W1,W2,feat
#define WQ4 (NE * F * F / 4)        // 131072 float4 per W
#define FQ4 (N_OBJ * F / 4)         // 262144 float4 for feat
__global__ __launch_bounds__(256) void k_cvt_all(const float* __restrict__ W0,
                                                 const float* __restrict__ W1,
                                                 const float* __restrict__ W2,
                                                 const float* __restrict__ feat,
                                                 unsigned short* __restrict__ Wb0,
                                                 unsigned short* __restrict__ Wb1,
                                                 unsigned short* __restrict__ Wb2,
                                                 unsigned short* __restrict__ featb) {
    int i = blockIdx.x * 256 + threadIdx.x;
    const float* s;
    unsigned short* d;
    int j;
    if (i < WQ4)            { s = W0;   d = Wb0;   j = i; }
    else if (i < 2 * WQ4)   { s = W1;   d = Wb1;   j = i - WQ4; }
    else if (i < 3 * WQ4)   { s = W2;   d = Wb2;   j = i - 2 * WQ4; }
    else                    { s = feat; d = featb; j = i - 3 * WQ4; }
    float4 v = ((const float4*)s)[j];
    ushort4 o;
    o.x = f2bf(v.x); o.y = f2bf(v.y); o.z = f2bf(v.z); o.w = f2bf(v.w);
    ((ushort4*)d)[j] = o;
}

// ---------------- per-layer: aggregate (mean over in-edges, per etype) ----------------
__global__ __launch_bounds__(256) void k_aggregate(const unsigned short* __restrict__ h_in,
                                                   const int* __restrict__ rowptr,
                                                   const int* __restrict__ deg,
                                                   const int* __restrict__ col,
                                                   const float* __restrict__ invdeg,
                                                   unsigned short* __restrict__ ah) {
    int wid = blockIdx.x * 4 + (threadIdx.x >> 6);   // == e*N_OBJ + n
    int lane = threadIdx.x & 63;                      // 64 lanes x 4 channels (8B)
    int e = wid >> 12;
    int n = wid & (N_OBJ - 1);
    int beg = rowptr[wid];
    int cnt = deg[wid];
    const int* cl = col + e * EPT + beg;
    const ushort4* h4 = (const ushort4*)h_in;
    float a0 = 0.f, a1 = 0.f, a2 = 0.f, a3 = 0.f;
    int k = 0;
    for (; k + 8 <= cnt; k += 8) {
        int s0 = cl[k],     s1 = cl[k + 1], s2 = cl[k + 2], s3 = cl[k + 3];
        int s4 = cl[k + 4], s5 = cl[k + 5], s6 = cl[k + 6], s7 = cl[k + 7];
        ushort4 v0 = h4[s0 * 64 + lane];
        ushort4 v1 = h4[s1 * 64 + lane];
        ushort4 v2 = h4[s2 * 64 + lane];
        ushort4 v3 = h4[s3 * 64 + lane];
        ushort4 v4 = h4[s4 * 64 + lane];
        ushort4 v5 = h4[s5 * 64 + lane];
        ushort4 v6 = h4[s6 * 64 + lane];
        ushort4 v7 = h4[s7 * 64 + lane];
        a0 += bf2f(v0.x) + bf2f(v1.x) + bf2f(v2.x) + bf2f(v3.x)
            + bf2f(v4.x) + bf2f(v5.x) + bf2f(v6.x) + bf2f(v7.x);
        a1 += bf2f(v0.y) + bf2f(v1.y) + bf2f(v2.y) + bf2f(v3.y)
            + bf2f(v4.y) + bf2f(v5.y) + bf2f(v6.y) + bf2f(v7.y);
        a2 += bf2f(v0.z) + bf2f(v1.z) + bf2f(v2.z) + bf2f(v3.z)
            + bf2f(v4.z) + bf2f(v5.z) + bf2f(v6.z) + bf2f(v7.z);
        a3 += bf2f(v0.w) + bf2f(v1.w) + bf2f(v2.w) + bf2f(v3.w)
            + bf2f(v4.w) + bf2f(v5.w) + bf2f(v6.w) + bf2f(v7.w);
    }
    for (; k < cnt; ++k) {
        ushort4 v = h4[cl[k] * 64 + lane];
        a0 += bf2f(v.x); a1 += bf2f(v.y); a2 += bf2f(v.z); a3 += bf2f(v.w);
    }
    float sc = invdeg[wid];
    ushort4 o;
    o.x = f2bf(a0 * sc); o.y = f2bf(a1 * sc); o.z = f2bf(a2 * sc); o.w = f2bf(a3 * sc);
    ((ushort4*)ah)[n * (KCAT / 4) + e * (F / 4) + lane] = o;
}

// ---------------- per-layer GEMM (bf16 MFMA): C = relu(AH x Wcat^T + bias_mask) ----------------
// 64x64 tile, BK=64, double-buffered swizzled LDS, one barrier per K-step.
// 4 waves; wave w owns m-sub w (16 rows) x 4 n-subs. Grid (64,4) = 256 blocks.
template <int OUTBF>
__global__ __launch_bounds__(256, 4) void k_gemm(const unsigned short* __restrict__ A,
                                                 const unsigned short* __restrict__ Wb,
                                                 const float* __restrict__ bias,
                                                 const unsigned int* __restrict__ bmask,
                                                 void* __restrict__ Cout) {
    __shared__ short As[2][64 * 64];   // 8 KB per buffer, swizzled rows (128 B)
    __shared__ short Bs[2][64 * 64];
    int m0 = blockIdx.x * 64, n0 = blockIdx.y * 64;
    int t = threadIdx.x;
    int wave = t >> 6, lane = t & 63;
    int r = lane & 15, g = lane >> 4;
    // staging: thread t owns frags (row0,seg0) and (row1,seg0); 8 threads = 128 B run
    int row0 = t >> 3, seg0 = t & 7;
    int row1 = row0 + 32;
    int wA0 = swz(row0, seg0), wA1 = swz(row1, seg0);

    const short* Ap = (const short*)A;
    const short* Wp = (const short*)Wb;
    const short* arp0 = Ap + (size_t)(m0 + row0) * KCAT + seg0 * 8;
    const short* arp1 = Ap + (size_t)(m0 + row1) * KCAT + seg0 * 8;
    int brow0 = (n0 + row0) * F + seg0 * 8;
    int brow1 = (n0 + row1) * F + seg0 * 8;

    f4v acc[4];
#pragma unroll
    for (int i = 0; i < 4; ++i) acc[i] = (f4v){0.f, 0.f, 0.f, 0.f};

    {   // prologue: stage K-step 0 (kb=0 -> e=0, f0=0)
        s8v a0 = *(const s8v*)(arp0);
        s8v a1 = *(const s8v*)(arp1);
        s8v b0 = *(const s8v*)(Wp + brow0);
        s8v b1 = *(const s8v*)(Wp + brow1);
        *(s8v*)&As[0][wA0] = a0; *(s8v*)&As[0][wA1] = a1;
        *(s8v*)&Bs[0][wA0] = b0; *(s8v*)&Bs[0][wA1] = b1;
    }
    __syncthreads();
#pragma unroll 1
    for (int ks = 0; ks < 32; ++ks) {
        int cur = ks & 1;
        s8v a0, a1, b0, b1;
        if (ks < 31) {   // issue next-step global loads (overlap with MFMA below)
            int kb = (ks + 1) * 64;
            int woff = ((kb >> 8) << 16) + (kb & 255);   // e*F*F + f0
            a0 = *(const s8v*)(arp0 + kb);
            a1 = *(const s8v*)(arp1 + kb);
            b0 = *(const s8v*)(Wp + woff + brow0);
            b1 = *(const s8v*)(Wp + woff + brow1);
        }
        const short* as = As[cur];
        const short* bs = Bs[cur];
#pragma unroll
        for (int kk = 0; kk < 2; ++kk) {
            s8v af = *(const s8v*)&as[swz(wave * 16 + r, kk * 4 + g)];
#pragma unroll
            for (int n = 0; n < 4; ++n) {
                s8v bf = *(const s8v*)&bs[swz(n * 16 + r, kk * 4 + g)];
                acc[n] = __builtin_amdgcn_mfma_f32_16x16x32_bf16(af, bf, acc[n], 0, 0, 0);
            }
        }
        if (ks < 31) {   // write NEXT buffer (its last readers finished at prev barrier)
            *(s8v*)&As[cur ^ 1][wA0] = a0; *(s8v*)&As[cur ^ 1][wA1] = a1;
            *(s8v*)&Bs[cur ^ 1][wA0] = b0; *(s8v*)&Bs[cur ^ 1][wA1] = b1;
        }
        __syncthreads();
    }
    // epilogue: C/D layout col=lane&15, row=(lane>>4)*4+reg (m89-verified)
    int mb = m0 + wave * 16 + g * 4;
    unsigned int msk[4];
#pragma unroll
    for (int reg = 0; reg < 4; ++reg) msk[reg] = bmask[mb + reg];
#pragma unroll
    for (int n = 0; n < 4; ++n) {
        int coln = n0 + n * 16 + r;
        float bcol[NE];
#pragma unroll
        for (int e = 0; e < NE; ++e) bcol[e] = bias[e * F + coln];
#pragma unroll
        for (int reg = 0; reg < 4; ++reg) {
            float v = acc[n][reg];
#pragma unroll
            for (int e = 0; e < NE; ++e)
                if ((msk[reg] >> e) & 1) v += bcol[e];
            v = fmaxf(v, 0.f);
            if (OUTBF) ((unsigned short*)Cout)[(size_t)(mb + reg) * F + coln] = f2bf(v);
            else       ((float*)Cout)[(size_t)(mb + reg) * F + coln] = v;
        }
    }
}

// ---------------- fc1 GEMV: x-chunk in LDS, pure w-stream ----------------
// Grid (FNCH=64, 256/FRJ=32); block: stage 64 KB x-chunk, stream 8 w-rows.
__global__ __launch_bounds__(256) void k_fc1(const float* __restrict__ Wf,
                                             const float* __restrict__ flat,
                                             float* __restrict__ zpart) {
    __shared__ float xs[FCH];   // 64 KB -> 2 blocks/CU
    int c = blockIdx.x;
    int jg = blockIdx.y;
    int t = threadIdx.x;
    const float4* fp = (const float4*)(flat + (size_t)c * FCH);
    float4* xs4 = (float4*)xs;
#pragma unroll
    for (int q = 0; q < FCH / 4 / 256; ++q) xs4[q * 256 + t] = fp[q * 256 + t];
    __syncthreads();
    float accs[FRJ];
#pragma unroll
    for (int rr = 0; rr < FRJ; ++rr) {
        const float4* wp = (const float4*)(Wf + (size_t)(jg * FRJ + rr) * FC1_K
                                              + (size_t)c * FCH);
        float s = 0.0f;
#pragma unroll 4
        for (int it = 0; it < FCH / 4 / 256; ++it) {   // 16 iters
            int q = it * 256 + t;
            float4 w4 = wp[q];
            float4 x4 = xs4[q];
            s = fmaf(w4.x, x4.x,
                fmaf(w4.y, x4.y,
                fmaf(w4.z, x4.z,
                fmaf(w4.w, x4.w, s))));
        }
        accs[rr] = s;
    }
    __shared__ float red[4][FRJ];
    int lane = t & 63, wv = t >> 6;
#pragma unroll
    for (int rr = 0; rr < FRJ; ++rr) {
        float s = accs[rr];
#pragma unroll
        for (int off = 32; off > 0; off >>= 1) s += __shfl_down(s, off, 64);
        if (lane == 0) red[wv][rr] = s;
    }
    __syncthreads();
    if (t < FRJ) {
        float s = red[0][t] + red[1][t] + red[2][t] + red[3][t];
        zpart[c * 256 + jg * FRJ + t] = s;
    }
}

__global__ __launch_bounds__(256) void k_final(const float* __restrict__ zpart,
                                               const float* __restrict__ fc1_b,
                                               const float* __restrict__ fc2_w,
                                               const float* __restrict__ fc2_b,
                                               float* __restrict__ out) {
    __shared__ float z[256];
    int t = threadIdx.x;
    float s = fc1_b[t];
#pragma unroll
    for (int c = 0; c < FNCH; ++c) s += zpart[c * 256 + t];
    z[t] = fmaxf(s, 0.0f);
    __syncthreads();
    if (t < C_OUT) {
        float acc = fc2_b[t];
        for (int k = 0; k < 256; ++k) acc = fmaf(fc2_w[t * 256 + k], z[k], acc);
        out[t] = 1.0f / (1.0f + expf(-acc));
    }
}

extern "C" void kernel_launch(void* const* d_in, const int* in_sizes, int n_in,
                              void* d_out, int out_size, void* d_ws, size_t ws_size,
                              hipStream_t stream) {
    const float* feat  = (const float*)d_in[0];
    const int*   edges = (const int*)d_in[1];
    const float* W0    = (const float*)d_in[2];
    const float* b0    = (const float*)d_in[3];
    const float* W1    = (const float*)d_in[4];
    const float* b1    = (const float*)d_in[5];
    const float* W2    = (const float*)d_in[6];
    const float* b2    = (const float*)d_in[7];
    const float* fc1_w = (const float*)d_in[8];
    const float* fc1_b = (const float*)d_in[9];
    const float* fc2_w = (const float*)d_in[10];
    const float* fc2_b = (const float*)d_in[11];
    float* out = (float*)d_out;

    char* ws = (char*)d_ws;
    size_t off = 0;
    auto alloc = [&](size_t bytes) {
        void* p = ws + off;
        off = (off + bytes + 255) & ~(size_t)255;
        return p;
    };
    int*            deg    = (int*)            alloc(NE * N_OBJ * 4);
    int*            rowptr = (int*)            alloc(NE * N_OBJ * 4);
    int*            cursor = (int*)            alloc(NE * N_OBJ * 4);
    float*          invdeg = (float*)          alloc(NE * N_OBJ * 4);
    int*            col    = (int*)            alloc(NE * EPT * 4);
    unsigned int*   bmask  = (unsigned int*)   alloc(N_OBJ * 4);
    float*          zpart  = (float*)          alloc(FNCH * 256 * 4);
    unsigned short* Wb0    = (unsigned short*) alloc((size_t)NE * F * F * 2);
    unsigned short* Wb1    = (unsigned short*) alloc((size_t)NE * F * F * 2);
    unsigned short* Wb2    = (unsigned short*) alloc((size_t)NE * F * F * 2);
    unsigned short* featb  = (unsigned short*) alloc((size_t)N_OBJ * F * 2);
    unsigned short* h_ba   = (unsigned short*) alloc((size_t)N_OBJ * F * 2);
    unsigned short* h_bb   = (unsigned short*) alloc((size_t)N_OBJ * F * 2);
    float*          h_f32  = (float*)          alloc((size_t)N_OBJ * F * 4);
    unsigned short* ah     = (unsigned short*) alloc((size_t)N_OBJ * KCAT * 2);
    (void)ws_size; (void)in_sizes; (void)n_in; (void)out_size;

    hipMemsetAsync(deg, 0, NE * N_OBJ * 4, stream);
    k_count_deg<<<NE * EPT / 256, 256, 0, stream>>>(edges, deg);
    k_scan<<<NE, 256, 0, stream>>>(deg, rowptr, cursor, invdeg);
    k_fill<<<NE * EPT / 256, 256, 0, stream>>>(edges, cursor, col);
    k_bmask<<<N_OBJ / 256, 256, 0, stream>>>(deg, bmask);
    k_cvt_all<<<(3 * WQ4 + FQ4) / 256, 256, 0, stream>>>(W0, W1, W2, feat,
                                                         Wb0, Wb1, Wb2, featb);

    dim3 ggrid(N_OBJ / 64, F / 64);   // 256 blocks
    int agrid = NE * N_OBJ / 4;       // one wave per (e,n)

    // layer 0
    k_aggregate<<<agrid, 256, 0, stream>>>(featb, rowptr, deg, col, invdeg, ah);
    k_gemm<1><<<ggrid, 256, 0, stream>>>(ah, Wb0, b0, bmask, h_ba);
    // layer 1
    k_aggregate<<<agrid, 256, 0, stream>>>(h_ba, rowptr, deg, col, invdeg, ah);
    k_gemm<1><<<ggrid, 256, 0, stream>>>(ah, Wb1, b1, bmask, h_bb);
    // layer 2 (fp32 out for fc1)
    k_aggregate<<<agrid, 256, 0, stream>>>(h_bb, rowptr, deg, col, invdeg, ah);
    k_gemm<0><<<ggrid, 256, 0, stream>>>(ah, Wb2, b2, bmask, h_f32);

    dim3 fgrid(FNCH, 256 / FRJ);      // (64, 32) = 2048 blocks
    k_fc1<<<fgrid, 256, 0, stream>>>(fc1_w, h_f32, zpart);
    k_final<<<1, 256, 0, stream>>>(zpart, fc1_b, fc2_w, fc2_b, out);
}